// Round 2
// baseline (1682.632 us; speedup 1.0000x reference)
//
#include <hip/hip_runtime.h>
#include <hip/hip_bf16.h>

#define F_IN 512
#define NB 128              // dst nodes per bucket
#define SRC_BITS 17         // N <= 131072
#define SRC_MASK ((1 << SRC_BITS) - 1)

// ---------------- lin1: h0 = relu(x @ W1^T + b1), rn0 = 1/max(||h0||,1e-12) --------------
__global__ __launch_bounds__(256) void lin1_kernel(
    const float* __restrict__ x, const float* __restrict__ w1,
    const float* __restrict__ b1, float* __restrict__ h0,
    float* __restrict__ rn0, int N) {
  __shared__ float sW[16 * F_IN];
  for (int i = threadIdx.x; i < 16 * F_IN / 4; i += 256)
    ((float4*)sW)[i] = ((const float4*)w1)[i];
  __syncthreads();

  int wave = (blockIdx.x * 256 + threadIdx.x) >> 6;
  int lane = threadIdx.x & 63;
  int j = lane & 15;
  int g = lane >> 4;
  int node = wave * 4 + g;
  if (node >= N) return;

  const float4* xr = (const float4*)(x + (size_t)node * F_IN);
  float acc[16];
#pragma unroll
  for (int k = 0; k < 16; ++k) acc[k] = 0.f;

#pragma unroll
  for (int t = 0; t < 8; ++t) {
    float4 xv = xr[t * 16 + j];
#pragma unroll
    for (int k = 0; k < 16; ++k) {
      float4 wv = *(const float4*)&sW[k * F_IN + t * 64 + j * 4];
      acc[k] = fmaf(xv.x, wv.x, fmaf(xv.y, wv.y, fmaf(xv.z, wv.z, fmaf(xv.w, wv.w, acc[k]))));
    }
  }
#pragma unroll
  for (int s = 1; s < 16; s <<= 1) {
#pragma unroll
    for (int k = 0; k < 16; ++k) acc[k] += __shfl_xor(acc[k], s, 64);
  }
  float hv = 0.f;
#pragma unroll
  for (int k = 0; k < 16; ++k)
    if (j == k) hv = acc[k];
  hv += b1[j];
  hv = fmaxf(hv, 0.f);

  float ns = hv * hv;
#pragma unroll
  for (int s = 1; s < 16; s <<= 1) ns += __shfl_xor(ns, s, 64);

  h0[(size_t)node * 16 + j] = hv;
  if (j == 0) rn0[node] = 1.f / fmaxf(sqrtf(ns), 1e-12f);
}

// ---------------- bucketed edge-list build ----------------
__global__ void bzero_kernel(int* __restrict__ p, int n) {
  int i = blockIdx.x * blockDim.x + threadIdx.x;
  if (i < n) p[i] = 0;
}

__global__ __launch_bounds__(256) void bhist_kernel(
    const int* __restrict__ dst, int* __restrict__ bcount, int E, int nb) {
  __shared__ int hist[1024];
  for (int i = threadIdx.x; i < nb; i += 256) hist[i] = 0;
  __syncthreads();
  for (int e = blockIdx.x * 256 + threadIdx.x; e < E; e += gridDim.x * 256)
    atomicAdd(&hist[dst[e] >> 7], 1);
  __syncthreads();
  for (int i = threadIdx.x; i < nb; i += 256) {
    int v = hist[i];
    if (v) atomicAdd(&bcount[i], v);
  }
}

__global__ __launch_bounds__(1024) void bscan_kernel(
    const int* __restrict__ bcount, int* __restrict__ boff,
    int* __restrict__ cur, int nb) {
  __shared__ int s[1024];
  int t = threadIdx.x;
  int v = (t < nb) ? bcount[t] : 0;
  s[t] = v;
  __syncthreads();
  for (int st = 1; st < 1024; st <<= 1) {
    int a = (t >= st) ? s[t - st] : 0;
    __syncthreads();
    s[t] += a;
    __syncthreads();
  }
  if (t < nb) { boff[t] = s[t] - v; cur[t] = s[t] - v; }
}

__global__ __launch_bounds__(256) void bappend_kernel(
    const int* __restrict__ src, const int* __restrict__ dst,
    int* __restrict__ cur, int* __restrict__ elist, int E) {
  int e = blockIdx.x * 256 + threadIdx.x;
  if (e < E) {
    int d = dst[e];
    int slot = atomicAdd(&cur[d >> 7], 1);
    elist[slot] = src[e] | ((d & (NB - 1)) << SRC_BITS);
  }
}

// ---------------- AGNN propagation: one block per 128-node bucket ----------------
// 16 lanes per edge (j = feature), LDS softmax accumulators, self-loop in finalize.
template <bool FUSE>
__global__ __launch_bounds__(256) void prop_kernel(
    const float* __restrict__ hin, const float* __restrict__ rnin,
    const int* __restrict__ boff, const int* __restrict__ bcount,
    const int* __restrict__ elist, const float* __restrict__ beta_ptr,
    float* __restrict__ hout, float* __restrict__ rnout,
    const float* __restrict__ w2, const float* __restrict__ b2,
    float* __restrict__ out, int N) {
  __shared__ float sh[NB][17];    // h[dst] (padded stride 17)
  __shared__ float snum[NB][17];  // softmax numerator
  __shared__ float srn[NB];
  __shared__ float sden[NB];

  int b = blockIdx.x;
  int node0 = b * NB;
  int nn = min(NB, N - node0);
  int t = threadIdx.x;
  int lane = t & 63;
  int j = lane & 15;   // feature / class
  int grp = t >> 4;    // 16 edge-groups per block

  for (int i = t; i < nn * 16; i += 256) {
    int n = i >> 4, f = i & 15;
    sh[n][f] = hin[(size_t)(node0 + n) * 16 + f];
    snum[n][f] = 0.f;
  }
  for (int i = t; i < nn; i += 256) {
    srn[i] = rnin[node0 + i];
    sden[i] = 0.f;
  }
  __syncthreads();

  float beta = beta_ptr ? beta_ptr[0] : 1.0f;
  int base = boff[b];
  int cnt = bcount[b];

  for (int i = grp; i < cnt; i += 16) {
    int pk = elist[base + i];
    int s = pk & SRC_MASK;
    int ld = pk >> SRC_BITS;
    float hs = hin[(size_t)s * 16 + j];
    float dt = hs * sh[ld][j];
    dt += __shfl_xor(dt, 1, 64);
    dt += __shfl_xor(dt, 2, 64);
    dt += __shfl_xor(dt, 4, 64);
    dt += __shfl_xor(dt, 8, 64);
    float ex = __expf(beta * dt * rnin[s] * srn[ld]);
    atomicAdd(&snum[ld][j], ex * hs);
    if (j == 0) atomicAdd(&sden[ld], ex);
  }
  __syncthreads();

  for (int i = grp; i < nn; i += 16) {
    float hd = sh[i][j];
    float ss = hd * hd;
    ss += __shfl_xor(ss, 1, 64);
    ss += __shfl_xor(ss, 2, 64);
    ss += __shfl_xor(ss, 4, 64);
    ss += __shfl_xor(ss, 8, 64);
    float rn = srn[i];
    float es = __expf(beta * ss * rn * rn);  // self-loop weight
    float o = (snum[i][j] + es * hd) / (sden[i] + es);
    if (!FUSE) {
      hout[(size_t)(node0 + i) * 16 + j] = o;
      float ns = o * o;
      ns += __shfl_xor(ns, 1, 64);
      ns += __shfl_xor(ns, 2, 64);
      ns += __shfl_xor(ns, 4, 64);
      ns += __shfl_xor(ns, 8, 64);
      if (j == 0) rnout[node0 + i] = 1.f / fmaxf(sqrtf(ns), 1e-12f);
    } else {
      // lin2 + log_softmax, class = j
      float lg = b2[j];
      int gb = lane & 48;
#pragma unroll
      for (int m = 0; m < 16; ++m)
        lg = fmaf(__shfl(o, gb + m, 64), w2[j * 16 + m], lg);
      float mx = lg;
      mx = fmaxf(mx, __shfl_xor(mx, 1, 64));
      mx = fmaxf(mx, __shfl_xor(mx, 2, 64));
      mx = fmaxf(mx, __shfl_xor(mx, 4, 64));
      mx = fmaxf(mx, __shfl_xor(mx, 8, 64));
      float exl = __expf(lg - mx);
      float sm = exl;
      sm += __shfl_xor(sm, 1, 64);
      sm += __shfl_xor(sm, 2, 64);
      sm += __shfl_xor(sm, 4, 64);
      sm += __shfl_xor(sm, 8, 64);
      out[(size_t)(node0 + i) * 16 + j] = lg - mx - logf(sm);
    }
  }
}

extern "C" void kernel_launch(void* const* d_in, const int* in_sizes, int n_in,
                              void* d_out, int out_size, void* d_ws, size_t ws_size,
                              hipStream_t stream) {
  const float* x     = (const float*)d_in[0];
  const int*   ei    = (const int*)d_in[1];
  const float* w1    = (const float*)d_in[2];
  const float* b1    = (const float*)d_in[3];
  const float* w2    = (const float*)d_in[4];
  const float* b2    = (const float*)d_in[5];
  const float* beta2 = (const float*)d_in[6];
  float* out = (float*)d_out;

  const int N = in_sizes[0] / F_IN;   // 100000
  const int E = in_sizes[1] / 2;      // 3200000
  const int* src = ei;
  const int* dst = ei + E;
  const int nb = (N + NB - 1) / NB;   // 782 buckets (<= 1024)

  char* ws = (char*)d_ws;
  size_t wo = 0;
  auto take = [&](size_t bytes) -> void* {
    void* p = ws + wo;
    wo = (wo + bytes + 255) & ~(size_t)255;
    return p;
  };
  int*   bcount = (int*)take((size_t)nb * 4);
  int*   boff   = (int*)take((size_t)nb * 4);
  int*   cur    = (int*)take((size_t)nb * 4);
  int*   elist  = (int*)take((size_t)E * 4);
  float* h0     = (float*)take((size_t)N * 16 * 4);
  float* rn0    = (float*)take((size_t)N * 4);
  float* h1     = (float*)take((size_t)N * 16 * 4);
  float* rn1    = (float*)take((size_t)N * 4);

  lin1_kernel<<<(N + 15) / 16, 256, 0, stream>>>(x, w1, b1, h0, rn0, N);

  bzero_kernel<<<(nb + 255) / 256, 256, 0, stream>>>(bcount, nb);
  bhist_kernel<<<512, 256, 0, stream>>>(dst, bcount, E, nb);
  bscan_kernel<<<1, 1024, 0, stream>>>(bcount, boff, cur, nb);
  bappend_kernel<<<(E + 255) / 256, 256, 0, stream>>>(src, dst, cur, elist, E);

  prop_kernel<false><<<nb, 256, 0, stream>>>(
      h0, rn0, boff, bcount, elist, nullptr, h1, rn1, nullptr, nullptr, nullptr, N);
  prop_kernel<true><<<nb, 256, 0, stream>>>(
      h1, rn1, boff, bcount, elist, beta2, nullptr, nullptr, w2, b2, out, N);
}

// Round 3
// 374.515 us; speedup vs baseline: 4.4928x; 4.4928x over previous
//
#include <hip/hip_runtime.h>
#include <hip/hip_bf16.h>

#define F_IN 512
#define NB 128              // dst nodes per bucket
#define SRC_BITS 17         // N <= 131072
#define SRC_MASK ((1 << SRC_BITS) - 1)
#define T_APP 8192          // edges per bappend block

// ---------------- lin1: h0 = relu(x @ W1^T + b1), rn0 = 1/max(||h0||,1e-12) --------------
__global__ __launch_bounds__(256) void lin1_kernel(
    const float* __restrict__ x, const float* __restrict__ w1,
    const float* __restrict__ b1, float* __restrict__ h0,
    float* __restrict__ rn0, int N) {
  __shared__ float sW[16 * F_IN];
  for (int i = threadIdx.x; i < 16 * F_IN / 4; i += 256)
    ((float4*)sW)[i] = ((const float4*)w1)[i];
  __syncthreads();

  int wave = (blockIdx.x * 256 + threadIdx.x) >> 6;
  int lane = threadIdx.x & 63;
  int j = lane & 15;
  int g = lane >> 4;
  int node = wave * 4 + g;
  if (node >= N) return;

  const float4* xr = (const float4*)(x + (size_t)node * F_IN);
  float acc[16];
#pragma unroll
  for (int k = 0; k < 16; ++k) acc[k] = 0.f;

#pragma unroll
  for (int t = 0; t < 8; ++t) {
    float4 xv = xr[t * 16 + j];
#pragma unroll
    for (int k = 0; k < 16; ++k) {
      float4 wv = *(const float4*)&sW[k * F_IN + t * 64 + j * 4];
      acc[k] = fmaf(xv.x, wv.x, fmaf(xv.y, wv.y, fmaf(xv.z, wv.z, fmaf(xv.w, wv.w, acc[k]))));
    }
  }
#pragma unroll
  for (int s = 1; s < 16; s <<= 1) {
#pragma unroll
    for (int k = 0; k < 16; ++k) acc[k] += __shfl_xor(acc[k], s, 64);
  }
  float hv = 0.f;
#pragma unroll
  for (int k = 0; k < 16; ++k)
    if (j == k) hv = acc[k];
  hv += b1[j];
  hv = fmaxf(hv, 0.f);

  float ns = hv * hv;
#pragma unroll
  for (int s = 1; s < 16; s <<= 1) ns += __shfl_xor(ns, s, 64);

  h0[(size_t)node * 16 + j] = hv;
  if (j == 0) rn0[node] = 1.f / fmaxf(sqrtf(ns), 1e-12f);
}

// ---------------- edge build: bucket hist -> scan -> binned append -> in-bucket sort ------
__global__ void bzero_kernel(int* __restrict__ p, int n) {
  int i = blockIdx.x * blockDim.x + threadIdx.x;
  if (i < n) p[i] = 0;
}

__global__ __launch_bounds__(256) void bhist_kernel(
    const int* __restrict__ dst, int* __restrict__ bcount, int E, int nb) {
  __shared__ int hist[1024];
  for (int i = threadIdx.x; i < nb; i += 256) hist[i] = 0;
  __syncthreads();
  for (int e = blockIdx.x * 256 + threadIdx.x; e < E; e += gridDim.x * 256)
    atomicAdd(&hist[dst[e] >> 7], 1);
  __syncthreads();
  for (int i = threadIdx.x; i < nb; i += 256) {
    int v = hist[i];
    if (v) atomicAdd(&bcount[i], v);
  }
}

__global__ __launch_bounds__(1024) void bscan_kernel(
    const int* __restrict__ bcount, int* __restrict__ boff,
    int* __restrict__ gcur, int* __restrict__ offg, int N, int nb, int E) {
  __shared__ int s[1024];
  int t = threadIdx.x;
  int v = (t < nb) ? bcount[t] : 0;
  s[t] = v;
  __syncthreads();
  for (int st = 1; st < 1024; st <<= 1) {
    int a = (t >= st) ? s[t - st] : 0;
    __syncthreads();
    s[t] += a;
    __syncthreads();
  }
  if (t < nb) { boff[t] = s[t] - v; gcur[t] = s[t] - v; }
  if (t == 0) offg[N] = E;
}

// per-block local counting, one chunk reservation per (block, bucket)
__global__ __launch_bounds__(512) void bappend_kernel(
    const int* __restrict__ src, const int* __restrict__ dst,
    int* __restrict__ gcur, int* __restrict__ elist, int E, int nb) {
  __shared__ int hist[1024], base[1024], curl[1024];
  int t = threadIdx.x;
  int e0 = blockIdx.x * T_APP;
  int e1 = min(E, e0 + T_APP);
  for (int i = t; i < nb; i += 512) hist[i] = 0;
  __syncthreads();
  for (int i = e0 + t; i < e1; i += 512) atomicAdd(&hist[dst[i] >> 7], 1);
  __syncthreads();
  for (int i = t; i < nb; i += 512) {
    int c = hist[i];
    base[i] = c ? atomicAdd(&gcur[i], c) : 0;
    curl[i] = 0;
  }
  __syncthreads();
  for (int i = e0 + t; i < e1; i += 512) {
    int d = dst[i];
    int b = d >> 7;
    int slot = base[b] + atomicAdd(&curl[b], 1);
    elist[slot] = src[i] | ((d & (NB - 1)) << SRC_BITS);
  }
}

// one block per bucket: counting-sort by local dst -> node-sorted CSR + node offsets
__global__ __launch_bounds__(256) void bsort_kernel(
    const int* __restrict__ elist, const int* __restrict__ boff,
    const int* __restrict__ bcount, int* __restrict__ csr,
    int* __restrict__ offg, int N) {
  __shared__ int hist[NB], scn[NB], cur[NB];
  int b = blockIdx.x, t = threadIdx.x;
  int base = boff[b], cnt = bcount[b];
  int node0 = b * NB, nn = min(NB, N - node0);
  if (t < NB) hist[t] = 0;
  __syncthreads();
  for (int i = t; i < cnt; i += 256) atomicAdd(&hist[elist[base + i] >> SRC_BITS], 1);
  __syncthreads();
  if (t < NB) scn[t] = hist[t];
  __syncthreads();
  for (int st = 1; st < NB; st <<= 1) {
    int v = (t >= st && t < NB) ? scn[t - st] : 0;
    __syncthreads();
    if (t < NB) scn[t] += v;
    __syncthreads();
  }
  if (t < NB) {
    int ex = scn[t] - hist[t];
    cur[t] = ex;
    if (t < nn) offg[node0 + t] = base + ex;
  }
  __syncthreads();
  for (int i = t; i < cnt; i += 256) {
    int pk = elist[base + i];
    int ld = pk >> SRC_BITS;
    int slot = atomicAdd(&cur[ld], 1);
    csr[base + slot] = pk & SRC_MASK;
  }
}

// ---------------- AGNN propagation (one wave per dst node, CSR gather) ----------------
template <bool FUSE>
__global__ __launch_bounds__(256) void prop_kernel(
    const float* __restrict__ hin, const float* __restrict__ rnin,
    const int* __restrict__ off, const int* __restrict__ csr,
    const float* __restrict__ beta_ptr,
    float* __restrict__ hout, float* __restrict__ rnout,
    const float* __restrict__ w2, const float* __restrict__ b2,
    float* __restrict__ out, int N) {
  int d = (blockIdx.x * 256 + threadIdx.x) >> 6;
  int lane = threadIdx.x & 63;
  int j = lane & 15;
  int e = lane >> 4;
  if (d >= N) return;

  float beta = beta_ptr ? beta_ptr[0] : 1.0f;
  float hd = hin[(size_t)d * 16 + j];
  float rnd = rnin[d];

  float ss = hd * hd;
#pragma unroll
  for (int s = 1; s < 16; s <<= 1) ss += __shfl_xor(ss, s, 64);

  float den, num;
  if (e == 0) {
    float es = __expf(beta * ss * rnd * rnd);  // self-loop
    den = es;
    num = es * hd;
  } else {
    den = 0.f;
    num = 0.f;
  }

  float brnd = beta * rnd;
  int base = off[d];
  int dg = off[d + 1] - base;
  for (int i = e; i < dg; i += 4) {
    int s = csr[base + i];
    float hs = hin[(size_t)s * 16 + j];
    float dt = hs * hd;
    dt += __shfl_xor(dt, 1, 64);
    dt += __shfl_xor(dt, 2, 64);
    dt += __shfl_xor(dt, 4, 64);
    dt += __shfl_xor(dt, 8, 64);
    float ex = __expf(brnd * dt * rnin[s]);
    den += ex;
    num = fmaf(ex, hs, num);
  }
  num += __shfl_xor(num, 16, 64);
  num += __shfl_xor(num, 32, 64);
  den += __shfl_xor(den, 16, 64);
  den += __shfl_xor(den, 32, 64);
  float o = num / den;

  if (!FUSE) {
    if (e == 0) hout[(size_t)d * 16 + j] = o;
    float ns = o * o;
#pragma unroll
    for (int s = 1; s < 16; s <<= 1) ns += __shfl_xor(ns, s, 64);
    if (lane == 0) rnout[d] = 1.f / fmaxf(sqrtf(ns), 1e-12f);
  } else {
    float lg = b2[j];
    int gb = lane & 48;
#pragma unroll
    for (int m = 0; m < 16; ++m)
      lg = fmaf(__shfl(o, gb + m, 64), w2[j * 16 + m], lg);
    float mx = lg;
#pragma unroll
    for (int s = 1; s < 16; s <<= 1) mx = fmaxf(mx, __shfl_xor(mx, s, 64));
    float exl = __expf(lg - mx);
    float sm = exl;
#pragma unroll
    for (int s = 1; s < 16; s <<= 1) sm += __shfl_xor(sm, s, 64);
    if (e == 0) out[(size_t)d * 16 + j] = lg - mx - logf(sm);
  }
}

extern "C" void kernel_launch(void* const* d_in, const int* in_sizes, int n_in,
                              void* d_out, int out_size, void* d_ws, size_t ws_size,
                              hipStream_t stream) {
  const float* x     = (const float*)d_in[0];
  const int*   ei    = (const int*)d_in[1];
  const float* w1    = (const float*)d_in[2];
  const float* b1    = (const float*)d_in[3];
  const float* w2    = (const float*)d_in[4];
  const float* b2    = (const float*)d_in[5];
  const float* beta2 = (const float*)d_in[6];
  float* out = (float*)d_out;

  const int N = in_sizes[0] / F_IN;   // 100000
  const int E = in_sizes[1] / 2;      // 3200000
  const int* src = ei;
  const int* dst = ei + E;
  const int nb = (N + NB - 1) / NB;   // 782

  char* ws = (char*)d_ws;
  size_t wo = 0;
  auto take = [&](size_t bytes) -> void* {
    void* p = ws + wo;
    wo = (wo + bytes + 255) & ~(size_t)255;
    return p;
  };
  int*   bcount = (int*)take((size_t)nb * 4);
  int*   boff   = (int*)take((size_t)nb * 4);
  int*   gcur   = (int*)take((size_t)nb * 4);
  int*   offg   = (int*)take((size_t)(N + 1) * 4);
  int*   csr    = (int*)take((size_t)E * 4);
  int*   elist  = (int*)take((size_t)E * 4);   // dead after bsort; h1/rn1 alias it
  float* h0     = (float*)take((size_t)N * 16 * 4);
  float* rn0    = (float*)take((size_t)N * 4);
  float* h1     = (float*)(elist);             // alias (elist dead before prop1)
  float* rn1    = (float*)(elist + (size_t)N * 16);

  lin1_kernel<<<(N + 15) / 16, 256, 0, stream>>>(x, w1, b1, h0, rn0, N);

  bzero_kernel<<<(nb + 255) / 256, 256, 0, stream>>>(bcount, nb);
  bhist_kernel<<<512, 256, 0, stream>>>(dst, bcount, E, nb);
  bscan_kernel<<<1, 1024, 0, stream>>>(bcount, boff, gcur, offg, N, nb, E);
  bappend_kernel<<<(E + T_APP - 1) / T_APP, 512, 0, stream>>>(src, dst, gcur, elist, E, nb);
  bsort_kernel<<<nb, 256, 0, stream>>>(elist, boff, bcount, csr, offg, N);

  prop_kernel<false><<<(N + 3) / 4, 256, 0, stream>>>(
      h0, rn0, offg, csr, nullptr, h1, rn1, nullptr, nullptr, nullptr, N);
  prop_kernel<true><<<(N + 3) / 4, 256, 0, stream>>>(
      h1, rn1, offg, csr, beta2, nullptr, nullptr, w2, b2, out, N);
}

// Round 4
// 293.585 us; speedup vs baseline: 5.7313x; 1.2757x over previous
//
#include <hip/hip_runtime.h>
#include <hip/hip_bf16.h>

#define F_IN 512
#define NB 128              // dst nodes per bucket
#define SRC_BITS 17         // N <= 131072
#define SRC_MASK ((1 << SRC_BITS) - 1)
#define T_APP 8192          // edges per bappend block

typedef unsigned int uint;

__device__ __forceinline__ uint f2bf(float f) {
  uint u = __float_as_uint(f);
  return (u + 0x7fffu + ((u >> 16) & 1u)) >> 16;  // RNE
}
__device__ __forceinline__ float bflo(uint u) { return __uint_as_float(u << 16); }
__device__ __forceinline__ float bfhi(uint u) { return __uint_as_float(u & 0xffff0000u); }

// ---------------- lin1: h0 = relu(x @ W1^T + b1) -> bf16 rows, rn0 = 1/max(||h0||,1e-12) ----
__global__ __launch_bounds__(256) void lin1_kernel(
    const float* __restrict__ x, const float* __restrict__ w1,
    const float* __restrict__ b1, uint* __restrict__ h0b,
    float* __restrict__ rn0, int N) {
  __shared__ float sW[16 * F_IN];
  for (int i = threadIdx.x; i < 16 * F_IN / 4; i += 256)
    ((float4*)sW)[i] = ((const float4*)w1)[i];
  __syncthreads();

  int wave = (blockIdx.x * 256 + threadIdx.x) >> 6;
  int lane = threadIdx.x & 63;
  int j = lane & 15;
  int g = lane >> 4;
  int node = wave * 4 + g;
  if (node >= N) return;

  const float4* xr = (const float4*)(x + (size_t)node * F_IN);
  float acc[16];
#pragma unroll
  for (int k = 0; k < 16; ++k) acc[k] = 0.f;

#pragma unroll
  for (int t = 0; t < 8; ++t) {
    float4 xv = xr[t * 16 + j];
#pragma unroll
    for (int k = 0; k < 16; ++k) {
      float4 wv = *(const float4*)&sW[k * F_IN + t * 64 + j * 4];
      acc[k] = fmaf(xv.x, wv.x, fmaf(xv.y, wv.y, fmaf(xv.z, wv.z, fmaf(xv.w, wv.w, acc[k]))));
    }
  }
#pragma unroll
  for (int s = 1; s < 16; s <<= 1) {
#pragma unroll
    for (int k = 0; k < 16; ++k) acc[k] += __shfl_xor(acc[k], s, 64);
  }
  float hv = 0.f;
#pragma unroll
  for (int k = 0; k < 16; ++k)
    if (j == k) hv = acc[k];
  hv += b1[j];
  hv = fmaxf(hv, 0.f);

  float ns = hv * hv;
#pragma unroll
  for (int s = 1; s < 16; s <<= 1) ns += __shfl_xor(ns, s, 64);

  float hp = __shfl_xor(hv, 1, 64);  // partner feature (j^1)
  if (!(j & 1))                      // even j packs (j, j+1)
    h0b[(size_t)node * 8 + (j >> 1)] = f2bf(hv) | (f2bf(hp) << 16);
  if (j == 0) rn0[node] = 1.f / fmaxf(sqrtf(ns), 1e-12f);
}

// ---------------- edge build: bucket hist -> scan -> binned append -> in-bucket sort ------
__global__ void bzero_kernel(int* __restrict__ p, int n) {
  int i = blockIdx.x * blockDim.x + threadIdx.x;
  if (i < n) p[i] = 0;
}

__global__ __launch_bounds__(256) void bhist_kernel(
    const int* __restrict__ dst, int* __restrict__ bcount, int E, int nb) {
  __shared__ int hist[1024];
  for (int i = threadIdx.x; i < nb; i += 256) hist[i] = 0;
  __syncthreads();
  for (int e = blockIdx.x * 256 + threadIdx.x; e < E; e += gridDim.x * 256)
    atomicAdd(&hist[dst[e] >> 7], 1);
  __syncthreads();
  for (int i = threadIdx.x; i < nb; i += 256) {
    int v = hist[i];
    if (v) atomicAdd(&bcount[i], v);
  }
}

__global__ __launch_bounds__(1024) void bscan_kernel(
    const int* __restrict__ bcount, int* __restrict__ boff,
    int* __restrict__ gcur, int* __restrict__ offg, int N, int nb, int E) {
  __shared__ int s[1024];
  int t = threadIdx.x;
  int v = (t < nb) ? bcount[t] : 0;
  s[t] = v;
  __syncthreads();
  for (int st = 1; st < 1024; st <<= 1) {
    int a = (t >= st) ? s[t - st] : 0;
    __syncthreads();
    s[t] += a;
    __syncthreads();
  }
  if (t < nb) { boff[t] = s[t] - v; gcur[t] = s[t] - v; }
  if (t == 0) offg[N] = E;
}

__global__ __launch_bounds__(512) void bappend_kernel(
    const int* __restrict__ src, const int* __restrict__ dst,
    int* __restrict__ gcur, int* __restrict__ elist, int E, int nb) {
  __shared__ int hist[1024], base[1024], curl[1024];
  int t = threadIdx.x;
  int e0 = blockIdx.x * T_APP;
  int e1 = min(E, e0 + T_APP);
  for (int i = t; i < nb; i += 512) hist[i] = 0;
  __syncthreads();
  for (int i = e0 + t; i < e1; i += 512) atomicAdd(&hist[dst[i] >> 7], 1);
  __syncthreads();
  for (int i = t; i < nb; i += 512) {
    int c = hist[i];
    base[i] = c ? atomicAdd(&gcur[i], c) : 0;
    curl[i] = 0;
  }
  __syncthreads();
  for (int i = e0 + t; i < e1; i += 512) {
    int d = dst[i];
    int b = d >> 7;
    int slot = base[b] + atomicAdd(&curl[b], 1);
    elist[slot] = src[i] | ((d & (NB - 1)) << SRC_BITS);
  }
}

__global__ __launch_bounds__(256) void bsort_kernel(
    const int* __restrict__ elist, const int* __restrict__ boff,
    const int* __restrict__ bcount, int* __restrict__ csr,
    int* __restrict__ offg, int N) {
  __shared__ int hist[NB], scn[NB], cur[NB];
  int b = blockIdx.x, t = threadIdx.x;
  int base = boff[b], cnt = bcount[b];
  int node0 = b * NB, nn = min(NB, N - node0);
  if (t < NB) hist[t] = 0;
  __syncthreads();
  for (int i = t; i < cnt; i += 256) atomicAdd(&hist[elist[base + i] >> SRC_BITS], 1);
  __syncthreads();
  if (t < NB) scn[t] = hist[t];
  __syncthreads();
  for (int st = 1; st < NB; st <<= 1) {
    int v = (t >= st && t < NB) ? scn[t - st] : 0;
    __syncthreads();
    if (t < NB) scn[t] += v;
    __syncthreads();
  }
  if (t < NB) {
    int ex = scn[t] - hist[t];
    cur[t] = ex;
    if (t < nn) offg[node0 + t] = base + ex;
  }
  __syncthreads();
  for (int i = t; i < cnt; i += 256) {
    int pk = elist[base + i];
    int ld = pk >> SRC_BITS;
    int slot = atomicAdd(&cur[ld], 1);
    csr[base + slot] = pk & SRC_MASK;
  }
}

// ---------------- AGNN propagation: wave per dst node, 8 edge-slots x 8 lanes ----------
// lane = 8*e + p : p = bf16 feature-pair (features 2p, 2p+1), e = edge slot.
template <bool FUSE>
__global__ __launch_bounds__(256) void prop_kernel(
    const uint* __restrict__ hb, const float* __restrict__ rnin,
    const int* __restrict__ off, const int* __restrict__ csr,
    const float* __restrict__ beta_ptr,
    uint* __restrict__ houtb, float* __restrict__ rnout,
    const float* __restrict__ w2, const float* __restrict__ b2,
    float* __restrict__ out, int N) {
  __shared__ float sw2t[256];  // transposed: sw2t[m*16+c] = w2[c*16+m]
  __shared__ float sb2[16];
  if (FUSE) {
    int t = threadIdx.x;
    if (t < 256) {
      int c = t & 15, m = t >> 4;
      sw2t[m * 16 + c] = w2[c * 16 + m];
    }
    if (t < 16) sb2[t] = b2[t];
    __syncthreads();
  }

  int d = (blockIdx.x * 256 + threadIdx.x) >> 6;
  int lane = threadIdx.x & 63;
  int p = lane & 7;    // feature pair
  int e = lane >> 3;   // 8 edge slots
  if (d >= N) return;

  float beta = beta_ptr ? beta_ptr[0] : 1.0f;
  uint hdu = hb[(size_t)d * 8 + p];
  float hd0 = bflo(hdu), hd1 = bfhi(hdu);
  float rnd = rnin[d];

  // self dot |h_d|^2 (8-lane group reduce)
  float ss = fmaf(hd0, hd0, hd1 * hd1);
  ss += __shfl_xor(ss, 1, 64);
  ss += __shfl_xor(ss, 2, 64);
  ss += __shfl_xor(ss, 4, 64);

  float den = 0.f, num0 = 0.f, num1 = 0.f;
  if (e == 0) {
    float es = __expf(beta * ss * rnd * rnd);  // self-loop weight
    den = es;
    num0 = es * hd0;
    num1 = es * hd1;
  }

  float brnd = beta * rnd;
  int base = off[d];
  int dg = off[d + 1] - base;
  for (int i = e; i < dg; i += 8) {
    int s = csr[base + i];
    uint hsu = hb[(size_t)s * 8 + p];
    float hs0 = bflo(hsu), hs1 = bfhi(hsu);
    float dt = fmaf(hs0, hd0, hs1 * hd1);
    dt += __shfl_xor(dt, 1, 64);
    dt += __shfl_xor(dt, 2, 64);
    dt += __shfl_xor(dt, 4, 64);
    float ex = __expf(brnd * dt * rnin[s]);
    den += ex;                       // identical across the 8 lanes of this slot
    num0 = fmaf(ex, hs0, num0);
    num1 = fmaf(ex, hs1, num1);
  }
  // combine the 8 edge slots (lanes with same p)
#pragma unroll
  for (int st = 8; st < 64; st <<= 1) {
    num0 += __shfl_xor(num0, st, 64);
    num1 += __shfl_xor(num1, st, 64);
    den  += __shfl_xor(den,  st, 64);
  }
  float inv = 1.f / den;
  float o0 = num0 * inv, o1 = num1 * inv;

  if (!FUSE) {
    if (e == 0) houtb[(size_t)d * 8 + p] = f2bf(o0) | (f2bf(o1) << 16);
    float ns = fmaf(o0, o0, o1 * o1);
    ns += __shfl_xor(ns, 1, 64);
    ns += __shfl_xor(ns, 2, 64);
    ns += __shfl_xor(ns, 4, 64);
    if (lane == 0) rnout[d] = 1.f / fmaxf(sqrtf(ns), 1e-12f);
  } else {
    // lin2: classes c0=2p, c1=2p+1 per lane (redundant across edge-slot groups)
    float lg0 = sb2[2 * p], lg1 = sb2[2 * p + 1];
    int gb = lane & 56;  // own 8-lane group base
#pragma unroll
    for (int m = 0; m < 16; ++m) {
      float om = (m & 1) ? __shfl(o1, gb + (m >> 1), 64) : __shfl(o0, gb + (m >> 1), 64);
      lg0 = fmaf(om, sw2t[m * 16 + 2 * p], lg0);
      lg1 = fmaf(om, sw2t[m * 16 + 2 * p + 1], lg1);
    }
    float mx = fmaxf(lg0, lg1);
    mx = fmaxf(mx, __shfl_xor(mx, 1, 64));
    mx = fmaxf(mx, __shfl_xor(mx, 2, 64));
    mx = fmaxf(mx, __shfl_xor(mx, 4, 64));
    float sm = __expf(lg0 - mx) + __expf(lg1 - mx);
    sm += __shfl_xor(sm, 1, 64);
    sm += __shfl_xor(sm, 2, 64);
    sm += __shfl_xor(sm, 4, 64);
    float ls = logf(sm);
    if (e == 0) {
      float2 r = make_float2(lg0 - mx - ls, lg1 - mx - ls);
      *(float2*)&out[(size_t)d * 16 + 2 * p] = r;
    }
  }
}

extern "C" void kernel_launch(void* const* d_in, const int* in_sizes, int n_in,
                              void* d_out, int out_size, void* d_ws, size_t ws_size,
                              hipStream_t stream) {
  const float* x     = (const float*)d_in[0];
  const int*   ei    = (const int*)d_in[1];
  const float* w1    = (const float*)d_in[2];
  const float* b1    = (const float*)d_in[3];
  const float* w2    = (const float*)d_in[4];
  const float* b2    = (const float*)d_in[5];
  const float* beta2 = (const float*)d_in[6];
  float* out = (float*)d_out;

  const int N = in_sizes[0] / F_IN;   // 100000
  const int E = in_sizes[1] / 2;      // 3200000
  const int* src = ei;
  const int* dst = ei + E;
  const int nb = (N + NB - 1) / NB;   // 782

  char* ws = (char*)d_ws;
  size_t wo = 0;
  auto take = [&](size_t bytes) -> void* {
    void* p = ws + wo;
    wo = (wo + bytes + 255) & ~(size_t)255;
    return p;
  };
  int*   bcount = (int*)take((size_t)nb * 4);
  int*   boff   = (int*)take((size_t)nb * 4);
  int*   gcur   = (int*)take((size_t)nb * 4);
  int*   offg   = (int*)take((size_t)(N + 1) * 4);
  int*   csr    = (int*)take((size_t)E * 4);
  int*   elist  = (int*)take((size_t)E * 4);   // dead after bsort; h1b/rn1 alias it
  uint*  h0b    = (uint*)take((size_t)N * 8 * 4);
  float* rn0    = (float*)take((size_t)N * 4);
  uint*  h1b    = (uint*)(elist);              // alias (elist dead before prop1)
  float* rn1    = (float*)(elist + (size_t)N * 8);

  lin1_kernel<<<(N + 15) / 16, 256, 0, stream>>>(x, w1, b1, h0b, rn0, N);

  bzero_kernel<<<(nb + 255) / 256, 256, 0, stream>>>(bcount, nb);
  bhist_kernel<<<512, 256, 0, stream>>>(dst, bcount, E, nb);
  bscan_kernel<<<1, 1024, 0, stream>>>(bcount, boff, gcur, offg, N, nb, E);
  bappend_kernel<<<(E + T_APP - 1) / T_APP, 512, 0, stream>>>(src, dst, gcur, elist, E, nb);
  bsort_kernel<<<nb, 256, 0, stream>>>(elist, boff, bcount, csr, offg, N);

  prop_kernel<false><<<(N + 3) / 4, 256, 0, stream>>>(
      h0b, rn0, offg, csr, nullptr, h1b, rn1, nullptr, nullptr, nullptr, N);
  prop_kernel<true><<<(N + 3) / 4, 256, 0, stream>>>(
      h1b, rn1, offg, csr, beta2, nullptr, nullptr, w2, b2, out, N);
}